// Round 1
// baseline (393.524 us; speedup 1.0000x reference)
//
#include <hip/hip_runtime.h>
#include <hip/hip_bf16.h>
#include <math.h>

// Problem constants (fixed by the reference file)
#define N     8192
#define F_IN  256
#define F_OUT 64
#define ALPHA 0.2f

// ---------------------------------------------------------------------------
// Kernel B: Wh = h @ W   [N, 64]; wh1[u] = Wh[u,:]@a[64:128]; wh2[u] = Wh[u,:]@a[0:64]
// Also writes per-block column-sum partials of Wh (for colsum reduction).
// Grid: 2048 blocks x 256 threads; each wave (64 lanes) computes one row of Wh.
// ---------------------------------------------------------------------------
__global__ __launch_bounds__(256) void gat_wh_kernel(
    const float* __restrict__ h,      // [N, 256]
    const float* __restrict__ W,      // [256, 64]
    const float* __restrict__ a,      // [128]
    float* __restrict__ Wh,           // [N, 64]
    float* __restrict__ wh1,          // [N]
    float* __restrict__ wh2,          // [N]
    float* __restrict__ colpart)      // [gridDim.x, 64]
{
    __shared__ float s_h[4][F_IN];    // 4 rows of h staged in LDS (4 KiB)
    __shared__ float s_cp[256];

    const int tid = threadIdx.x;
    const int wv  = tid >> 6;         // wave id 0..3 -> row within block
    const int ln  = tid & 63;         // lane 0..63  -> output feature
    const int u   = blockIdx.x * 4 + wv;

    // Stage this wave's h row into LDS (coalesced float4 per lane)
    const float4* hrow = (const float4*)(h + (size_t)u * F_IN);
    ((float4*)s_h[wv])[ln] = hrow[ln];
    __syncthreads();

    // Dot product: Wh[u, ln] = sum_k h[u,k] * W[k, ln]
    float acc = 0.f;
    const float4* sh4 = (const float4*)s_h[wv];
#pragma unroll 8
    for (int k4 = 0; k4 < F_IN / 4; ++k4) {
        float4 hv = sh4[k4];          // LDS broadcast (conflict-free)
        int k = k4 * 4;
        acc += hv.x * W[(k + 0) * F_OUT + ln];
        acc += hv.y * W[(k + 1) * F_OUT + ln];
        acc += hv.z * W[(k + 2) * F_OUT + ln];
        acc += hv.w * W[(k + 3) * F_OUT + ln];
    }

    // Store Wh row (coalesced 256B per wave)
    Wh[(size_t)u * F_OUT + ln] = acc;

    // wh1 (source term uses a[64:128]), wh2 (dest term uses a[0:64])
    float p1 = acc * a[F_OUT + ln];
    float p2 = acc * a[ln];
#pragma unroll
    for (int off = 32; off > 0; off >>= 1) {
        p1 += __shfl_down(p1, off);
        p2 += __shfl_down(p2, off);
    }
    if (ln == 0) {
        wh1[u] = p1;
        wh2[u] = p2;
    }

    // Per-block column-sum partial of Wh (sum over the block's 4 rows)
    s_cp[tid] = acc;
    __syncthreads();
    if (tid < 64) {
        colpart[(size_t)blockIdx.x * 64 + tid] =
            s_cp[tid] + s_cp[tid + 64] + s_cp[tid + 128] + s_cp[tid + 192];
    }
}

// ---------------------------------------------------------------------------
// Kernel C: colsum[f] = sum_b colpart[b][f].  Grid: 64 blocks x 256 threads.
// ---------------------------------------------------------------------------
__global__ __launch_bounds__(256) void gat_colsum_kernel(
    const float* __restrict__ colpart,   // [2048, 64]
    float* __restrict__ colsum)          // [64]
{
    __shared__ float r[256];
    const int f = blockIdx.x;
    const int tid = threadIdx.x;
    float s = 0.f;
    for (int b = tid; b < 2048; b += 256) s += colpart[(size_t)b * 64 + f];
    r[tid] = s;
    __syncthreads();
    if (tid < 128) r[tid] += r[tid + 128];
    __syncthreads();
    if (tid < 64) {
        float x = r[tid] + r[tid + 64];
#pragma unroll
        for (int off = 32; off > 0; off >>= 1) x += __shfl_down(x, off);
        if (tid == 0) colsum[f] = x;
    }
}

// ---------------------------------------------------------------------------
// Kernel D: per-row sparse attention aggregation.
//   out[u,f] = elu( (sum_edges w_i * Wh[i,f] + colsum[f]) / (sum_edges w_i + N) )
// with w_i = expm1(leakyrelu(wh1[u] + wh2[i])).
// One block (256 threads) per row. adj row streamed in 4 chunked passes of
// 2048 cols; edges compacted into LDS (capacity == chunk width -> no overflow).
// ---------------------------------------------------------------------------
#define CHUNK  2048
#define PASSES (N / CHUNK)     // 4

__global__ __launch_bounds__(256) void gat_main_kernel(
    const float* __restrict__ adj,     // [N, N]
    const float* __restrict__ Wh,      // [N, 64]
    const float* __restrict__ wh1,     // [N]
    const float* __restrict__ wh2,     // [N]
    const float* __restrict__ colsum,  // [64]
    float* __restrict__ out)           // [N, 64]
{
    __shared__ int   s_idx[CHUNK];     // 8 KiB
    __shared__ float s_w[CHUNK];       // 8 KiB
    __shared__ float s_red[256];       // 1 KiB
    __shared__ int   s_cnt;

    const int tid = threadIdx.x;
    const int u   = blockIdx.x;
    const int f   = tid & 63;          // feature
    const int g   = tid >> 6;          // edge-group (4 waves)

    const float wh1u = wh1[u];
    const float* __restrict__ arow = adj + (size_t)u * N;

    float acc  = 0.f;                  // partial of feature f (group g)
    float sumw = 0.f;                  // thread-local sum of edge weights

    for (int p = 0; p < PASSES; ++p) {
        if (tid == 0) s_cnt = 0;
        __syncthreads();

        // ---- phase 1: scan + compact edges of this 2048-col chunk ----
        const int base = p * CHUNK + tid * 8;
        float4 v0 = *(const float4*)(arow + base);
        float4 v1 = *(const float4*)(arow + base + 4);
        float vals[8] = {v0.x, v0.y, v0.z, v0.w, v1.x, v1.y, v1.z, v1.w};
#pragma unroll
        for (int j = 0; j < 8; ++j) {
            if (vals[j] != 0.f) {
                int col = base + j;
                float e = wh1u + wh2[col];
                e = (e >= 0.f) ? e : ALPHA * e;   // LeakyReLU
                float w = expm1f(e);              // exp(e) - 1
                sumw += w;
                int pos = atomicAdd(&s_cnt, 1);
                s_idx[pos] = col;
                s_w[pos]   = w;
            }
        }
        __syncthreads();
        const int nE = s_cnt;
        __syncthreads();   // all reads of s_cnt done before next pass resets it

        // ---- phase 2: feature-parallel accumulation over compacted edges ----
        for (int e = g; e < nE; e += 4) {
            acc += s_w[e] * Wh[(size_t)s_idx[e] * F_OUT + f];
        }
        // s_idx/s_w reads are protected from next pass's writes by the
        // __syncthreads() at the top of the next iteration.
    }

    // ---- block-reduce sumw ----
    s_red[tid] = sumw;
    __syncthreads();
    if (tid < 128) s_red[tid] += s_red[tid + 128];
    __syncthreads();
    if (tid < 64) {
        float x = s_red[tid] + s_red[tid + 64];
#pragma unroll
        for (int off = 32; off > 0; off >>= 1) x += __shfl_down(x, off);
        if (tid == 0) s_red[0] = x;
    }
    __syncthreads();
    const float denom = s_red[0] + (float)N;
    __syncthreads();   // done reading s_red[0]; safe to reuse

    // ---- block-reduce acc (4 groups -> 1) and epilogue ----
    s_red[tid] = acc;
    __syncthreads();
    if (tid < 64) {
        float tot = s_red[tid] + s_red[tid + 64] + s_red[tid + 128] + s_red[tid + 192];
        float val = (tot + colsum[tid]) / denom;
        // ELU (alpha=1): x>0 ? x : expm1(x)
        out[(size_t)u * F_OUT + tid] = (val > 0.f) ? val : expm1f(val);
    }
}

// ---------------------------------------------------------------------------
// Launch
// ---------------------------------------------------------------------------
extern "C" void kernel_launch(void* const* d_in, const int* in_sizes, int n_in,
                              void* d_out, int out_size, void* d_ws, size_t ws_size,
                              hipStream_t stream) {
    const float* h   = (const float*)d_in[0];   // [8192, 256]
    const float* adj = (const float*)d_in[1];   // [8192, 8192]
    const float* W   = (const float*)d_in[2];   // [256, 64]
    const float* a   = (const float*)d_in[3];   // [128, 1]
    float* out = (float*)d_out;                 // [8192, 64]

    // Workspace layout (floats)
    float* ws      = (float*)d_ws;
    float* Wh      = ws;                        // 524288
    float* wh1     = Wh + (size_t)N * F_OUT;    // 8192
    float* wh2     = wh1 + N;                   // 8192
    float* colpart = wh2 + N;                   // 2048*64 = 131072
    float* colsum  = colpart + 2048 * 64;       // 64

    gat_wh_kernel<<<N / 4, 256, 0, stream>>>(h, W, a, Wh, wh1, wh2, colpart);
    gat_colsum_kernel<<<64, 256, 0, stream>>>(colpart, colsum);
    gat_main_kernel<<<N, 256, 0, stream>>>(adj, Wh, wh1, wh2, colsum, out);
}